// Round 12
// baseline (170.168 us; speedup 1.0000x reference)
//
#include <hip/hip_runtime.h>

#define MDIM 2048   // B
#define KD   2560   // HEAD
#define NHID 2048   // N_HID
#define INF  512
#define NS   40     // K-tiles of 64

typedef __attribute__((ext_vector_type(16))) float f32x16;
typedef __attribute__((ext_vector_type(8))) short short8;
typedef __attribute__((ext_vector_type(4))) unsigned int u32x4;
typedef __attribute__((ext_vector_type(8))) unsigned short ushort8v;
typedef __attribute__((ext_vector_type(4))) unsigned short ushort4v;

#define AS1 __attribute__((address_space(1)))
#define AS3 __attribute__((address_space(3)))

__device__ __forceinline__ unsigned short f2bf(float f) {
    unsigned u = __float_as_uint(f);
    u += 0x7fffu + ((u >> 16) & 1u);
    return (unsigned short)(u >> 16);
}

// ---------------- merged prep: xc (blocks 0..2559) + Wm (blocks 2560..7679) ----------------
#define XCB 2560
__global__ void prep_all(const float* __restrict__ x, const float* __restrict__ h,
                         unsigned short* __restrict__ xc,
                         const float* __restrict__ Wg, const float* __restrict__ Wh,
                         const float* __restrict__ Wfg, const float* __restrict__ Wfh,
                         const float* __restrict__ Wp, const float* __restrict__ mask,
                         unsigned short* __restrict__ Wm) {
    if (blockIdx.x < XCB) {
        int idx = blockIdx.x * 256 + threadIdx.x;
        int e = idx * 8;
        int b = e / KD;
        int c = e - b * KD;
        const float* src = (c < INF) ? (x + (size_t)b * INF + c)
                                     : (h + (size_t)b * NHID + (c - INF));
        float4 v0 = *(const float4*)src;
        float4 v1 = *(const float4*)(src + 4);
        ushort8v o;
        o[0] = f2bf(v0.x); o[1] = f2bf(v0.y); o[2] = f2bf(v0.z); o[3] = f2bf(v0.w);
        o[4] = f2bf(v1.x); o[5] = f2bf(v1.y); o[6] = f2bf(v1.z); o[7] = f2bf(v1.w);
        *(ushort8v*)(xc + e) = o;
    } else {
        int idx = (blockIdx.x - XCB) * 256 + threadIdx.x;
        size_t e = (size_t)idx * 4;
        const size_t PL = (size_t)NHID * KD;
        int col = (int)(e % KD);
        float4 m;
        if (col < INF) m = *(const float4*)(mask + e);
        else           m = make_float4(1.f, 1.f, 1.f, 1.f);
        const float* Ws[5] = {Wg, Wh, Wfg, Wfh, Wp};
        #pragma unroll
        for (int k = 0; k < 5; ++k) {
            float4 w = *(const float4*)(Ws[k] + e);
            ushort4v o;
            o[0] = f2bf(w.x * m.x); o[1] = f2bf(w.y * m.y);
            o[2] = f2bf(w.z * m.z); o[3] = f2bf(w.w * m.w);
            *(ushort4v*)(Wm + k * PL + e) = o;
        }
    }
}

// ---------------- fused GEMM + epilogue: counted-lgkm intra-wave pipeline ----------------
// R11 base (256x64x5 tile, 8 waves 4Mx2N, 32x32x16, dbuf LDS, fused epilogue).
// All loop ds_reads are inline-asm ds_read_b128 (the ONLY lgkm ops in the body
// -> counts exact). Per s-iter: issue reads(s+1) [7], s_waitcnt lgkmcnt(7)
// (waits set s only), sched_barrier(0) [rule 18], 10 MFMA on set s. LDS pipe
// serves reads(s+1) DURING MFMA(s) -> pipes overlap instead of alternating.
// Addresses: 4 hoisted 32-bit LDS addrs; s-step is XOR-additive:
// cs(s)=cs(0)^(s<<5) bytes (deltas 32/96/32/96). Planes/A-buf1 via offset imm.
#define MFMA32(d, va, vb) d = __builtin_amdgcn_mfma_f32_32x32x16_bf16(va, vb, d, 0, 0, 0)

#define DSR(dst, addr, OFS) \
    asm volatile("ds_read_b128 %0, %1 offset:" OFS : "=v"(dst) : "v"(addr) : "memory")
#define LGKM7 do { asm volatile("s_waitcnt lgkmcnt(7)" ::: "memory"); \
                   __builtin_amdgcn_sched_barrier(0); } while (0)
#define LGKM0 do { asm volatile("s_waitcnt lgkmcnt(0)" ::: "memory"); \
                   __builtin_amdgcn_sched_barrier(0); } while (0)

__global__ __launch_bounds__(512, 2) void gemm_fused(
    const unsigned short* __restrict__ A,
    const unsigned short* __restrict__ Bm,
    const float* __restrict__ bg, const float* __restrict__ bh,
    const float* __restrict__ bfg, const float* __restrict__ bfh,
    const float* __restrict__ bp,
    float* __restrict__ out) {
    __shared__ unsigned short lsA[2][256 * 64];   // 64 KB, buf1 at +32768 B
    __shared__ unsigned short lsB0[320 * 64];     // 40 KB
    __shared__ unsigned short lsB1[320 * 64];     // 40 KB

    const int tid  = threadIdx.x;
    const int lane = tid & 63;
    const int w    = tid >> 6;       // 0..7
    const int wm   = w >> 1;         // 0..3
    const int wn   = w & 1;          // 0..1
    const int l31  = lane & 31;
    const int hi   = lane >> 5;
    const int l7   = lane & 7;
    const int u    = l31 >> 3;
    const int sc   = lane & 7;       // staging slot
    const int su   = lane >> 3;      // staging row-in-group
    const int m0   = blockIdx.y * 256;
    const int n0c  = blockIdx.x * 64;

    const int ar0 = (w >> 2) * 128 + (w & 3) * 8;   // + 32*j
    const int br0 = (w >> 1) * 80 + (w & 1) * 8;    // + 16*j

    // ---- hoisted per-lane staging source offsets (bytes) ----
    unsigned aOff[4], bOff[5];
    #pragma unroll
    for (int j = 0; j < 4; ++j) {
        const int r0 = ar0 + 32 * j;
        const int colv = ((sc ^ su ^ ((r0 >> 3) & 7)) << 3);
        aOff[j] = (unsigned)(((r0 + su) * KD + colv) * 2);
    }
    #pragma unroll
    for (int j = 0; j < 5; ++j) {
        const int r0 = br0 + 16 * j;
        const int grow = (r0 >> 6) * NHID + n0c + (r0 & 63);
        const int colv = ((sc ^ su ^ ((r0 >> 3) & 7)) << 3);
        bOff[j] = (unsigned)(((grow + su) * KD + colv) * 2);
    }
    const char* aBase = (const char*)A + (size_t)m0 * KD * 2;   // +128 B per staged tile
    const char* bBase = (const char*)Bm;

#define STG(buf) do { \
        _Pragma("unroll") \
        for (int j = 0; j < 4; ++j) \
            __builtin_amdgcn_global_load_lds( \
                (const AS1 unsigned int*)(aBase + aOff[j]), \
                (AS3 unsigned int*)(&lsA[buf][(ar0 + 32 * j) * 64]), 16, 0, 0); \
        _Pragma("unroll") \
        for (int j = 0; j < 5; ++j) \
            __builtin_amdgcn_global_load_lds( \
                (const AS1 unsigned int*)(bBase + bOff[j]), \
                (AS3 unsigned int*)((buf) ? &lsB1[(br0 + 16 * j) * 64] \
                                          : &lsB0[(br0 + 16 * j) * 64]), 16, 0, 0); \
        aBase += 128; bBase += 128; \
    } while (0)

    // ---- hoisted 32-bit LDS read addresses (s=0 state) ----
    const int arow = wm * 64 + l31;    // + 32*m
    const int brow = wn * 32 + l31;    // + 64*p (plane via offset imm 8192*p)
    const int keyB = (4 * wn + u) & 7;
    unsigned aA0 = (unsigned)(size_t)(AS3 const unsigned short*)
        &lsA[0][arow * 64 + ((hi ^ l7 ^ (u & 7)) << 3)];
    unsigned aA1 = (unsigned)(size_t)(AS3 const unsigned short*)
        &lsA[0][(arow + 32) * 64 + ((hi ^ l7 ^ ((4 + u) & 7)) << 3)];
    unsigned bB0a = (unsigned)(size_t)(AS3 const unsigned short*)
        &lsB0[brow * 64 + ((hi ^ l7 ^ keyB) << 3)];
    unsigned bB1a = (unsigned)(size_t)(AS3 const unsigned short*)
        &lsB1[brow * 64 + ((hi ^ l7 ^ keyB) << 3)];

#define XUP(D) do { aA0 ^= (D); aA1 ^= (D); bB0a ^= (D); bB1a ^= (D); } while (0)

#define ISSUE(SET, AOFS, BADDR) do { \
        DSR(SET[0], aA0, AOFS); DSR(SET[1], aA1, AOFS); \
        DSR(SET[2], BADDR, "0");     DSR(SET[3], BADDR, "8192"); \
        DSR(SET[4], BADDR, "16384"); DSR(SET[5], BADDR, "24576"); \
        DSR(SET[6], BADDR, "32768"); \
    } while (0)

    f32x16 acc[2][5] = {};

#define MM(SET) do { \
        short8 a0_ = __builtin_bit_cast(short8, SET[0]); \
        short8 a1_ = __builtin_bit_cast(short8, SET[1]); \
        __builtin_amdgcn_s_setprio(1); \
        _Pragma("unroll") \
        for (int p = 0; p < 5; ++p) { \
            short8 bp_ = __builtin_bit_cast(short8, SET[2 + p]); \
            MFMA32(acc[0][p], a0_, bp_); \
            MFMA32(acc[1][p], a1_, bp_); \
        } \
        __builtin_amdgcn_s_setprio(0); \
    } while (0)

#define ENDBAR() do { \
        asm volatile("s_waitcnt vmcnt(0)" ::: "memory"); \
        __builtin_amdgcn_s_barrier(); \
    } while (0)

// one K-tile: pipelined s-iters with counted lgkm (issue s+1, wait 7, MFMA s)
#define TILE(AOFS, BADDR, DO_STG, STGBUF) do { \
        u32x4 fX[7], fY[7]; \
        ISSUE(fX, AOFS, BADDR); \
        if (DO_STG) STG(STGBUF); \
        XUP(32); ISSUE(fY, AOFS, BADDR); \
        LGKM7; MM(fX); \
        XUP(96); ISSUE(fX, AOFS, BADDR); \
        LGKM7; MM(fY); \
        XUP(32); ISSUE(fY, AOFS, BADDR); \
        LGKM7; MM(fX); \
        XUP(96); \
        LGKM0; MM(fY); \
        ENDBAR(); \
    } while (0)

    // prologue: stage tile 0 -> buf 0
    STG(0);
    ENDBAR();

    for (int kt = 0; kt < NS; kt += 2) {
        TILE("0", bB0a, true, 1);                       // compute buf0, stage kt+1
        TILE("32768", bB1a, (kt + 2 < NS), 0);          // compute buf1, stage kt+2
    }

    // ---- fused epilogue (C/D: col = lane&31, row = (reg&3)+8*(reg>>2)+4*hi) ----
    const int col = n0c + wn * 32 + l31;
    const float bgv = bg[col];
    const float bhv = bh[col];
    const float bfv = bfg[col] + bfh[col];
    const float bpv = bp[col];
    const size_t PL = (size_t)MDIM * NHID;
    #pragma unroll
    for (int m = 0; m < 2; ++m) {
        #pragma unroll
        for (int q = 0; q < 4; ++q) {
            #pragma unroll
            for (int t = 0; t < 4; ++t) {
                const int e = q * 4 + t;
                const int row = m0 + wm * 64 + m * 32 + q * 8 + 4 * hi + t;
                float gx = acc[m][0][e] + bgv;
                float hx = acc[m][1][e] + bhv;
                float sx = acc[m][2][e] + acc[m][3][e] + bfv;
                float tg = __expf(-2.0f * fabsf(gx));
                float g  = __builtin_copysignf((1.0f - tg) / (1.0f + tg), gx);
                float th = __expf(-2.0f * fabsf(hx));
                float hh = __builtin_copysignf((1.0f - th) / (1.0f + th), hx);
                float gate = 1.0f / (1.0f + __expf(-sx));
                float nh = g * (1.0f - gate) + gate * hh;
                float y  = acc[m][4][e] + bpv + nh;
                out[(size_t)row * NHID + col]      = y;
                out[PL + (size_t)row * NHID + col] = nh;
            }
        }
    }
#undef STG
#undef XUP
#undef ISSUE
#undef MM
#undef ENDBAR
#undef TILE
}

extern "C" void kernel_launch(void* const* d_in, const int* in_sizes, int n_in,
                              void* d_out, int out_size, void* d_ws, size_t ws_size,
                              hipStream_t stream) {
    const float* x      = (const float*)d_in[0];
    const float* hidden = (const float*)d_in[1];
    const float* mask   = (const float*)d_in[2];
    const float* Wg     = (const float*)d_in[3];
    const float* bg     = (const float*)d_in[4];
    const float* Wh     = (const float*)d_in[5];
    const float* bh     = (const float*)d_in[6];
    const float* Wfg    = (const float*)d_in[7];
    const float* bfg    = (const float*)d_in[8];
    const float* Wfh    = (const float*)d_in[9];
    const float* bfh    = (const float*)d_in[10];
    const float* Wp     = (const float*)d_in[11];
    const float* bp     = (const float*)d_in[12];
    float* out = (float*)d_out;

    const size_t need = (size_t)MDIM * KD * 2 + (size_t)5 * NHID * KD * 2;
    if (ws_size < need) return;

    unsigned short* xc = (unsigned short*)d_ws;
    unsigned short* Wm = xc + (size_t)MDIM * KD;

    prep_all<<<XCB + NHID * KD / 4 / 256, 256, 0, stream>>>(
        x, hidden, xc, Wg, Wh, Wfg, Wfh, Wp, mask, Wm);
    dim3 grid(NHID / 64, MDIM / 256);
    gemm_fused<<<grid, 512, 0, stream>>>(xc, Wm, bg, bh, bfg, bfh, bp, out);
}

// Round 13
// 151.583 us; speedup vs baseline: 1.1226x; 1.1226x over previous
//
#include <hip/hip_runtime.h>

#define MDIM 2048   // B
#define KD   2560   // HEAD
#define NHID 2048   // N_HID
#define INF  512
#define BK   32
#define NT   80     // K-tiles of 32

typedef __attribute__((ext_vector_type(16))) float f32x16;
typedef __attribute__((ext_vector_type(8))) short short8;
typedef __attribute__((ext_vector_type(8))) unsigned short ushort8v;
typedef __attribute__((ext_vector_type(4))) unsigned short ushort4v;

#define AS1 __attribute__((address_space(1)))
#define AS3 __attribute__((address_space(3)))

__device__ __forceinline__ unsigned short f2bf(float f) {
    unsigned u = __float_as_uint(f);
    u += 0x7fffu + ((u >> 16) & 1u);
    return (unsigned short)(u >> 16);
}

// ---------------- merged prep: xc (blocks 0..2559) + Wm (blocks 2560..7679) ----------------
#define XCB 2560
__global__ void prep_all(const float* __restrict__ x, const float* __restrict__ h,
                         unsigned short* __restrict__ xc,
                         const float* __restrict__ Wg, const float* __restrict__ Wh,
                         const float* __restrict__ Wfg, const float* __restrict__ Wfh,
                         const float* __restrict__ Wp, const float* __restrict__ mask,
                         unsigned short* __restrict__ Wm) {
    if (blockIdx.x < XCB) {
        int idx = blockIdx.x * 256 + threadIdx.x;
        int e = idx * 8;
        int b = e / KD;
        int c = e - b * KD;
        const float* src = (c < INF) ? (x + (size_t)b * INF + c)
                                     : (h + (size_t)b * NHID + (c - INF));
        float4 v0 = *(const float4*)src;
        float4 v1 = *(const float4*)(src + 4);
        ushort8v o;
        o[0] = f2bf(v0.x); o[1] = f2bf(v0.y); o[2] = f2bf(v0.z); o[3] = f2bf(v0.w);
        o[4] = f2bf(v1.x); o[5] = f2bf(v1.y); o[6] = f2bf(v1.z); o[7] = f2bf(v1.w);
        *(ushort8v*)(xc + e) = o;
    } else {
        int idx = (blockIdx.x - XCB) * 256 + threadIdx.x;
        size_t e = (size_t)idx * 4;
        const size_t PL = (size_t)NHID * KD;
        int col = (int)(e % KD);
        float4 m;
        if (col < INF) m = *(const float4*)(mask + e);
        else           m = make_float4(1.f, 1.f, 1.f, 1.f);
        const float* Ws[5] = {Wg, Wh, Wfg, Wfh, Wp};
        #pragma unroll
        for (int k = 0; k < 5; ++k) {
            float4 w = *(const float4*)(Ws[k] + e);
            ushort4v o;
            o[0] = f2bf(w.x * m.x); o[1] = f2bf(w.y * m.y);
            o[2] = f2bf(w.z * m.z); o[3] = f2bf(w.w * m.w);
            *(ushort4v*)(Wm + k * PL + e) = o;
        }
    }
}

// ---------------- fused GEMM + epilogue: 2 blocks/CU for cross-block pipe overlap ----
// Mechanism (m114): independent co-resident blocks overlap MFMA and LDS pipes
// (time = max, not sum) because they are never barrier-synced with each other.
// BM=128, BN=64cols x 5 planes, BK=32, 256 threads (4 waves 2Mx2N), LDS 56KB
// double-buffered -> grid 512 = 2 blocks/CU, zero tail. Per-wave shape kept
// from R7/R11 (2x5 32x32 frags, acc=160). Swizzle for 4-slot (16B) rows:
// LDS[r][s] = G[r][s ^ ((r^(r>>2))&3)] -> lane-only keys both sides, reads hit
// the b128 4-cycle structural floor (even/odd bank-halves x 4 lanes/slot).
#define MFMA32(d, va, vb) d = __builtin_amdgcn_mfma_f32_32x32x16_bf16(va, vb, d, 0, 0, 0)

__global__ __launch_bounds__(256, 2) void gemm_fused(
    const unsigned short* __restrict__ A,
    const unsigned short* __restrict__ Bm,
    const float* __restrict__ bg, const float* __restrict__ bh,
    const float* __restrict__ bfg, const float* __restrict__ bfh,
    const float* __restrict__ bp,
    float* __restrict__ out) {
    __shared__ unsigned short lsA[2][128 * BK];   // 16 KB
    __shared__ unsigned short lsB[2][320 * BK];   // 40 KB

    const int tid  = threadIdx.x;
    const int lane = tid & 63;
    const int w    = tid >> 6;       // 0..3
    const int wm   = w >> 1;         // 0..1
    const int wn   = w & 1;          // 0..1
    const int l31  = lane & 31;
    const int hi   = lane >> 5;
    const int su   = lane >> 2;      // staging row-in-16-group (0..15)
    const int sc   = lane & 3;       // staging slot (16B units)
    const int m0   = blockIdx.y * 128;
    const int n0c  = blockIdx.x * 64;

    // ---- staging: instr covers 16 rows x 32 cols; src slot = sc ^ ((su^(su>>2))&3) ----
    const int skey = sc ^ ((su ^ (su >> 2)) & 3);
    const int ar0 = w * 32;          // + 16*j, j=0..1
    const int br0 = w * 80;          // + 16*j, j=0..4

    unsigned aOff[2], bOff[5];
    #pragma unroll
    for (int j = 0; j < 2; ++j)
        aOff[j] = (unsigned)((((ar0 + 16 * j) + su) * KD + skey * 8) * 2);
    #pragma unroll
    for (int j = 0; j < 5; ++j) {
        const int r0 = br0 + 16 * j;
        const int grow = (r0 >> 6) * NHID + n0c + (r0 & 63);
        bOff[j] = (unsigned)(((grow + su) * KD + skey * 8) * 2);
    }
    const char* aBase = (const char*)A + (size_t)m0 * KD * 2;   // +64 B per tile
    const char* bBase = (const char*)Bm;

#define STG(buf) do { \
        _Pragma("unroll") \
        for (int j = 0; j < 2; ++j) \
            __builtin_amdgcn_global_load_lds( \
                (const AS1 unsigned int*)(aBase + aOff[j]), \
                (AS3 unsigned int*)(&lsA[buf][(ar0 + 16 * j) * BK]), 16, 0, 0); \
        _Pragma("unroll") \
        for (int j = 0; j < 5; ++j) \
            __builtin_amdgcn_global_load_lds( \
                (const AS1 unsigned int*)(bBase + bOff[j]), \
                (AS3 unsigned int*)(&lsB[buf][(br0 + 16 * j) * BK]), 16, 0, 0); \
        aBase += 64; bBase += 64; \
    } while (0)

    // ---- fragment read offsets (bytes): row*64 + ((2s+hi)^kk)*16, kk lane-only ----
    const int arow = wm * 64 + l31;    // + 32*m
    const int brow = wn * 32 + l31;    // + 64*p
    const int kk = (l31 ^ (l31 >> 2)) & 3;
    unsigned aRd[2][2], bRd[2];
    #pragma unroll
    for (int s = 0; s < 2; ++s) {
        #pragma unroll
        for (int m = 0; m < 2; ++m)
            aRd[m][s] = (unsigned)((arow + 32 * m) * 64 + (((2 * s + hi) ^ kk) << 4));
        bRd[s] = (unsigned)(brow * 64 + (((2 * s + hi) ^ kk) << 4));
    }

    f32x16 acc[2][5] = {};

#define COMPUTE(bcl) do { \
        const char* baseA_ = (const char*)&lsA[bcl][0]; \
        const char* baseB_ = (const char*)&lsB[bcl][0]; \
        _Pragma("unroll") \
        for (int s = 0; s < 2; ++s) { \
            short8 av[2], bv[5]; \
            _Pragma("unroll") \
            for (int m = 0; m < 2; ++m) \
                av[m] = *(const short8*)(baseA_ + aRd[m][s]); \
            _Pragma("unroll") \
            for (int p = 0; p < 5; ++p) \
                bv[p] = *(const short8*)(baseB_ + bRd[s] + p * 4096); \
            __builtin_amdgcn_s_setprio(1); \
            _Pragma("unroll") \
            for (int m = 0; m < 2; ++m) \
                _Pragma("unroll") \
                for (int p = 0; p < 5; ++p) \
                    MFMA32(acc[m][p], av[m], bv[p]); \
            __builtin_amdgcn_s_setprio(0); \
        } \
    } while (0)

#define ENDBAR() do { \
        asm volatile("s_waitcnt vmcnt(0)" ::: "memory"); \
        __builtin_amdgcn_s_barrier(); \
    } while (0)

    // prologue: stage tile 0 -> buf 0
    STG(0);
    ENDBAR();

    for (int kt = 0; kt < NT; kt += 2) {
        STG(1);                          // stage kt+1 (kt+1 < NT always: NT even)
        COMPUTE(0);
        ENDBAR();
        if (kt + 2 < NT) STG(0);         // stage kt+2
        COMPUTE(1);
        ENDBAR();
    }

    // ---- fused epilogue (C/D: col = lane&31, row = (reg&3)+8*(reg>>2)+4*hi) ----
    const int col = n0c + wn * 32 + l31;
    const float bgv = bg[col];
    const float bhv = bh[col];
    const float bfv = bfg[col] + bfh[col];
    const float bpv = bp[col];
    const size_t PL = (size_t)MDIM * NHID;
    #pragma unroll
    for (int m = 0; m < 2; ++m) {
        #pragma unroll
        for (int q = 0; q < 4; ++q) {
            #pragma unroll
            for (int t = 0; t < 4; ++t) {
                const int e = q * 4 + t;
                const int row = m0 + wm * 64 + m * 32 + q * 8 + 4 * hi + t;
                float gx = acc[m][0][e] + bgv;
                float hx = acc[m][1][e] + bhv;
                float sx = acc[m][2][e] + acc[m][3][e] + bfv;
                float tg = __expf(-2.0f * fabsf(gx));
                float g  = __builtin_copysignf((1.0f - tg) / (1.0f + tg), gx);
                float th = __expf(-2.0f * fabsf(hx));
                float hh = __builtin_copysignf((1.0f - th) / (1.0f + th), hx);
                float gate = 1.0f / (1.0f + __expf(-sx));
                float nh = g * (1.0f - gate) + gate * hh;
                float y  = acc[m][4][e] + bpv + nh;
                out[(size_t)row * NHID + col]      = y;
                out[PL + (size_t)row * NHID + col] = nh;
            }
        }
    }
#undef STG
#undef COMPUTE
#undef ENDBAR
}

extern "C" void kernel_launch(void* const* d_in, const int* in_sizes, int n_in,
                              void* d_out, int out_size, void* d_ws, size_t ws_size,
                              hipStream_t stream) {
    const float* x      = (const float*)d_in[0];
    const float* hidden = (const float*)d_in[1];
    const float* mask   = (const float*)d_in[2];
    const float* Wg     = (const float*)d_in[3];
    const float* bg     = (const float*)d_in[4];
    const float* Wh     = (const float*)d_in[5];
    const float* bh     = (const float*)d_in[6];
    const float* Wfg    = (const float*)d_in[7];
    const float* bfg    = (const float*)d_in[8];
    const float* Wfh    = (const float*)d_in[9];
    const float* bfh    = (const float*)d_in[10];
    const float* Wp     = (const float*)d_in[11];
    const float* bp     = (const float*)d_in[12];
    float* out = (float*)d_out;

    const size_t need = (size_t)MDIM * KD * 2 + (size_t)5 * NHID * KD * 2;
    if (ws_size < need) return;

    unsigned short* xc = (unsigned short*)d_ws;
    unsigned short* Wm = xc + (size_t)MDIM * KD;

    prep_all<<<XCB + NHID * KD / 4 / 256, 256, 0, stream>>>(
        x, hidden, xc, Wg, Wh, Wfg, Wfh, Wp, mask, Wm);
    dim3 grid(NHID / 64, MDIM / 128);
    gemm_fused<<<grid, 256, 0, stream>>>(xc, Wm, bg, bh, bfg, bfh, bp, out);
}

// Round 14
// 141.187 us; speedup vs baseline: 1.2053x; 1.0736x over previous
//
#include <hip/hip_runtime.h>

#define MDIM 2048   // B
#define KD   2560   // HEAD
#define NHID 2048   // N_HID
#define INF  512
#define NS   40     // K-tiles of 64

typedef __attribute__((ext_vector_type(4))) float f32x4;
typedef __attribute__((ext_vector_type(8))) short short8;
typedef __attribute__((ext_vector_type(8))) unsigned short ushort8v;
typedef __attribute__((ext_vector_type(4))) unsigned short ushort4v;

#define AS1 __attribute__((address_space(1)))
#define AS3 __attribute__((address_space(3)))

__device__ __forceinline__ unsigned short f2bf(float f) {
    unsigned u = __float_as_uint(f);
    u += 0x7fffu + ((u >> 16) & 1u);
    return (unsigned short)(u >> 16);
}

// ---------------- merged prep: xc (blocks 0..2559) + Wm (blocks 2560..7679) ----------------
#define XCB 2560
__global__ void prep_all(const float* __restrict__ x, const float* __restrict__ h,
                         unsigned short* __restrict__ xc,
                         const float* __restrict__ Wg, const float* __restrict__ Wh,
                         const float* __restrict__ Wfg, const float* __restrict__ Wfh,
                         const float* __restrict__ Wp, const float* __restrict__ mask,
                         unsigned short* __restrict__ Wm) {
    if (blockIdx.x < XCB) {
        int idx = blockIdx.x * 256 + threadIdx.x;
        int e = idx * 8;
        int b = e / KD;
        int c = e - b * KD;
        const float* src = (c < INF) ? (x + (size_t)b * INF + c)
                                     : (h + (size_t)b * NHID + (c - INF));
        float4 v0 = *(const float4*)src;
        float4 v1 = *(const float4*)(src + 4);
        ushort8v o;
        o[0] = f2bf(v0.x); o[1] = f2bf(v0.y); o[2] = f2bf(v0.z); o[3] = f2bf(v0.w);
        o[4] = f2bf(v1.x); o[5] = f2bf(v1.y); o[6] = f2bf(v1.z); o[7] = f2bf(v1.w);
        *(ushort8v*)(xc + e) = o;
    } else {
        int idx = (blockIdx.x - XCB) * 256 + threadIdx.x;
        size_t e = (size_t)idx * 4;
        const size_t PL = (size_t)NHID * KD;
        int col = (int)(e % KD);
        float4 m;
        if (col < INF) m = *(const float4*)(mask + e);
        else           m = make_float4(1.f, 1.f, 1.f, 1.f);
        const float* Ws[5] = {Wg, Wh, Wfg, Wfh, Wp};
        #pragma unroll
        for (int k = 0; k < 5; ++k) {
            float4 w = *(const float4*)(Ws[k] + e);
            ushort4v o;
            o[0] = f2bf(w.x * m.x); o[1] = f2bf(w.y * m.y);
            o[2] = f2bf(w.z * m.z); o[3] = f2bf(w.w * m.w);
            *(ushort4v*)(Wm + k * PL + e) = o;
        }
    }
}

// ---------------- fused GEMM + epilogue: m201 phase skeleton + never-drain ledger ----
// Geometry (R6, minimal reads): 256x64x5 tile, 8 waves (2M x 4N), 16x16x32,
// per-wave 128x80 = acc[8][5]; every fragment read exactly ONCE per K-tile
// (A 16 + B 10 = 26 ds_read_b128/wave). bv0/bv1 held in regs across phases.
// Swizzle (R6-validated, 0 conflicts): stored key K(r)=r&7 via soff; read
// offset = (slot ^ l7)*16B.
// Phases per tile t (buffers bc=t&1, bo=bc^1):
//  P0: stage A(t+1)x2 -> vmcnt(7) [forces A(t),B(t); leaves A(t+1)2+B(t+1)5]
//      -> barrier -> read A(mh0,k0)x4 + B(k0)x5 -> barrier -> 20 MFMA -> barrier
//  P1: read A(mh0,k1)+B(k1) -> stage A(t+1)x2 -> barrier -> MFMA -> barrier
//  P2: read A(mh1,k0) -> stage B(t+2)x2 [lsB[bc] free: B-reads ended at P1] ->
//      barrier -> MFMA (bv0 held) -> barrier
//  P3: read A(mh1,k1) -> stage B(t+2)x3 -> barrier -> MFMA (bv1 held) -> barrier
// ONE vmcnt(7)/tile; B gets ~6 phases of HBM flight; never drains to 0.
#define MFMA16(d, va, vb) d = __builtin_amdgcn_mfma_f32_16x16x32_bf16(va, vb, d, 0, 0, 0)

__global__ __launch_bounds__(512, 2) void gemm_fused(
    const unsigned short* __restrict__ A,
    const unsigned short* __restrict__ Bm,
    const float* __restrict__ bg, const float* __restrict__ bh,
    const float* __restrict__ bfg, const float* __restrict__ bfh,
    const float* __restrict__ bp,
    float* __restrict__ out) {
    __shared__ unsigned short lsA[2][256 * 64];   // 64 KB
    __shared__ unsigned short lsB[2][320 * 64];   // 80 KB

    const int tid  = threadIdx.x;
    const int lane = tid & 63;
    const int w    = tid >> 6;       // 0..7
    const int wm   = w >> 2;         // 0..1  (M waves)
    const int wn   = w & 3;          // 0..3  (N col-quarter)
    const int lr   = lane & 15;
    const int kq   = lane >> 4;      // 0..3
    const int l7   = lane & 7;
    const int m0   = blockIdx.y * 256;
    const int n0c  = blockIdx.x * 64;

    const unsigned short* gA = A + (size_t)m0 * KD;
    // staging: 8 rows x 8 slots per instr; stored key K(r) = r&7 (R6-validated)
    const int soff = (lane >> 3) * KD + (((lane & 7) ^ (lane >> 3)) << 3);
    const int ar0 = (w >> 2) * 128 + (w & 3) * 8;   // + 32*j, j=0..3
    const int br0 = (w >> 1) * 80 + (w & 1) * 8;    // + 16*j, j=0..4

#define SA(j, t, b) __builtin_amdgcn_global_load_lds( \
        (const AS1 unsigned int*)(gA + (size_t)(ar0 + 32 * (j)) * KD + (t) * 64 + soff), \
        (AS3 unsigned int*)(&lsA[b][(ar0 + 32 * (j)) * 64]), 16, 0, 0)
#define SB(j, t, b) do { \
        const int r0_ = br0 + 16 * (j); \
        const int grow_ = (r0_ >> 6) * NHID + n0c + (r0_ & 63); \
        __builtin_amdgcn_global_load_lds( \
            (const AS1 unsigned int*)(Bm + (size_t)grow_ * KD + (t) * 64 + soff), \
            (AS3 unsigned int*)(&lsB[b][r0_ * 64]), 16, 0, 0); \
    } while (0)

    // reads: row key = row&7 = l7 for all read rows (all row strides mult of 8)
    const int c0 = ((0 + kq) ^ l7) << 3;   // k-half 0, ushort offset
    const int c1 = ((4 + kq) ^ l7) << 3;   // k-half 1
    const int arow = wm * 128 + lr;        // + 16*m
    const int browb = wn * 16 + lr;        // + 64*p

#define LDA(b, m, cs) (*(const short8*)&lsA[b][(arow + 16 * (m)) * 64 + (cs)])
#define LDB(b, p, cs) (*(const short8*)&lsB[b][((p) * 64 + browb) * 64 + (cs)])

#define BAR() do { __builtin_amdgcn_s_barrier(); \
                   __builtin_amdgcn_sched_barrier(0); } while (0)

    f32x4 acc[8][5] = {};

    // ---- prologue: A(0),B(0)->buf0; B(1)->buf1; force first 9, keep B(1) flying
    SA(0, 0, 0); SA(1, 0, 0); SA(2, 0, 0); SA(3, 0, 0);
    SB(0, 0, 0); SB(1, 0, 0); SB(2, 0, 0); SB(3, 0, 0); SB(4, 0, 0);
    SB(0, 1, 1); SB(1, 1, 1); SB(2, 1, 1); SB(3, 1, 1); SB(4, 1, 1);
    asm volatile("s_waitcnt vmcnt(5)" ::: "memory");
    __builtin_amdgcn_s_barrier();

    for (int kt = 0; kt < NS; ++kt) {
        const int bc = kt & 1, bo = bc ^ 1;
        short8 av[4], bv0[5], bv1[5];

        // ---- P0: stage A(kt+1) pair 1; counted wait; reads mh0/k0; MFMA ----
        if (kt < NS - 1) { SA(0, kt + 1, bo); SA(1, kt + 1, bo); }
        __builtin_amdgcn_sched_barrier(0);
        asm volatile("s_waitcnt vmcnt(7)" ::: "memory");
        BAR();
        #pragma unroll
        for (int i = 0; i < 4; ++i) av[i] = LDA(bc, i, c0);
        #pragma unroll
        for (int p = 0; p < 5; ++p) bv0[p] = LDB(bc, p, c0);
        BAR();
        __builtin_amdgcn_s_setprio(1);
        #pragma unroll
        for (int i = 0; i < 4; ++i)
            #pragma unroll
            for (int p = 0; p < 5; ++p) MFMA16(acc[i][p], av[i], bv0[p]);
        __builtin_amdgcn_s_setprio(0);
        BAR();

        // ---- P1: reads mh0/k1; stage A(kt+1) pair 2; MFMA ----
        #pragma unroll
        for (int i = 0; i < 4; ++i) av[i] = LDA(bc, i, c1);
        #pragma unroll
        for (int p = 0; p < 5; ++p) bv1[p] = LDB(bc, p, c1);
        if (kt < NS - 1) { SA(2, kt + 1, bo); SA(3, kt + 1, bo); }
        BAR();
        __builtin_amdgcn_s_setprio(1);
        #pragma unroll
        for (int i = 0; i < 4; ++i)
            #pragma unroll
            for (int p = 0; p < 5; ++p) MFMA16(acc[i][p], av[i], bv1[p]);
        __builtin_amdgcn_s_setprio(0);
        BAR();

        // ---- P2: reads mh1/k0; stage B(kt+2) 2 ops (lsB[bc] B-reads done) ----
        #pragma unroll
        for (int i = 0; i < 4; ++i) av[i] = LDA(bc, 4 + i, c0);
        if (kt < NS - 2) { SB(0, kt + 2, bc); SB(1, kt + 2, bc); }
        BAR();
        __builtin_amdgcn_s_setprio(1);
        #pragma unroll
        for (int i = 0; i < 4; ++i)
            #pragma unroll
            for (int p = 0; p < 5; ++p) MFMA16(acc[4 + i][p], av[i], bv0[p]);
        __builtin_amdgcn_s_setprio(0);
        BAR();

        // ---- P3: reads mh1/k1; stage B(kt+2) 3 ops; MFMA ----
        #pragma unroll
        for (int i = 0; i < 4; ++i) av[i] = LDA(bc, 4 + i, c1);
        if (kt < NS - 2) { SB(2, kt + 2, bc); SB(3, kt + 2, bc); SB(4, kt + 2, bc); }
        BAR();
        __builtin_amdgcn_s_setprio(1);
        #pragma unroll
        for (int i = 0; i < 4; ++i)
            #pragma unroll
            for (int p = 0; p < 5; ++p) MFMA16(acc[4 + i][p], av[i], bv1[p]);
        __builtin_amdgcn_s_setprio(0);
        BAR();
    }

    // ---- fused epilogue (16x16 C/D: col = lane&15, row = m*16 + kq*4 + j) ----
    const int col = n0c + wn * 16 + lr;
    const float bgv = bg[col];
    const float bhv = bh[col];
    const float bfv = bfg[col] + bfh[col];
    const float bpv = bp[col];
    const size_t PL = (size_t)MDIM * NHID;
    #pragma unroll
    for (int m = 0; m < 8; ++m) {
        #pragma unroll
        for (int j = 0; j < 4; ++j) {
            const int row = m0 + wm * 128 + m * 16 + kq * 4 + j;
            float gx = acc[m][0][j] + bgv;
            float hx = acc[m][1][j] + bhv;
            float sx = acc[m][2][j] + acc[m][3][j] + bfv;
            float tg = __expf(-2.0f * fabsf(gx));
            float g  = __builtin_copysignf((1.0f - tg) / (1.0f + tg), gx);
            float th = __expf(-2.0f * fabsf(hx));
            float hh = __builtin_copysignf((1.0f - th) / (1.0f + th), hx);
            float gate = 1.0f / (1.0f + __expf(-sx));
            float nh = g * (1.0f - gate) + gate * hh;
            float y  = acc[m][4][j] + bpv + nh;
            out[(size_t)row * NHID + col]      = y;
            out[PL + (size_t)row * NHID + col] = nh;
        }
    }
#undef SA
#undef SB
#undef LDA
#undef LDB
#undef BAR
}

extern "C" void kernel_launch(void* const* d_in, const int* in_sizes, int n_in,
                              void* d_out, int out_size, void* d_ws, size_t ws_size,
                              hipStream_t stream) {
    const float* x      = (const float*)d_in[0];
    const float* hidden = (const float*)d_in[1];
    const float* mask   = (const float*)d_in[2];
    const float* Wg     = (const float*)d_in[3];
    const float* bg     = (const float*)d_in[4];
    const float* Wh     = (const float*)d_in[5];
    const float* bh     = (const float*)d_in[6];
    const float* Wfg    = (const float*)d_in[7];
    const float* bfg    = (const float*)d_in[8];
    const float* Wfh    = (const float*)d_in[9];
    const float* bfh    = (const float*)d_in[10];
    const float* Wp     = (const float*)d_in[11];
    const float* bp     = (const float*)d_in[12];
    float* out = (float*)d_out;

    const size_t need = (size_t)MDIM * KD * 2 + (size_t)5 * NHID * KD * 2;
    if (ws_size < need) return;

    unsigned short* xc = (unsigned short*)d_ws;
    unsigned short* Wm = xc + (size_t)MDIM * KD;

    prep_all<<<XCB + NHID * KD / 4 / 256, 256, 0, stream>>>(
        x, hidden, xc, Wg, Wh, Wfg, Wfh, Wp, mask, Wm);
    dim3 grid(NHID / 64, MDIM / 256);
    gemm_fused<<<grid, 512, 0, stream>>>(xc, Wm, bg, bh, bfg, bfh, bp, out);
}

// Round 15
// 130.672 us; speedup vs baseline: 1.3022x; 1.0805x over previous
//
#include <hip/hip_runtime.h>

#define MDIM 2048   // B
#define KD   2560   // HEAD
#define NHID 2048   // N_HID
#define INF  512
#define NS   40     // K-tiles of 64

typedef __attribute__((ext_vector_type(4))) float f32x4;
typedef __attribute__((ext_vector_type(8))) short short8;
typedef __attribute__((ext_vector_type(8))) unsigned short ushort8v;
typedef __attribute__((ext_vector_type(4))) unsigned short ushort4v;

#define AS1 __attribute__((address_space(1)))
#define AS3 __attribute__((address_space(3)))

__device__ __forceinline__ unsigned short f2bf(float f) {
    unsigned u = __float_as_uint(f);
    u += 0x7fffu + ((u >> 16) & 1u);
    return (unsigned short)(u >> 16);
}

// ---------------- merged prep: xc (blocks 0..2559) + Wm (blocks 2560..7679) ----------------
#define XCB 2560
__global__ void prep_all(const float* __restrict__ x, const float* __restrict__ h,
                         unsigned short* __restrict__ xc,
                         const float* __restrict__ Wg, const float* __restrict__ Wh,
                         const float* __restrict__ Wfg, const float* __restrict__ Wfh,
                         const float* __restrict__ Wp, const float* __restrict__ mask,
                         unsigned short* __restrict__ Wm) {
    if (blockIdx.x < XCB) {
        int idx = blockIdx.x * 256 + threadIdx.x;
        int e = idx * 8;
        int b = e / KD;
        int c = e - b * KD;
        const float* src = (c < INF) ? (x + (size_t)b * INF + c)
                                     : (h + (size_t)b * NHID + (c - INF));
        float4 v0 = *(const float4*)src;
        float4 v1 = *(const float4*)(src + 4);
        ushort8v o;
        o[0] = f2bf(v0.x); o[1] = f2bf(v0.y); o[2] = f2bf(v0.z); o[3] = f2bf(v0.w);
        o[4] = f2bf(v1.x); o[5] = f2bf(v1.y); o[6] = f2bf(v1.z); o[7] = f2bf(v1.w);
        *(ushort8v*)(xc + e) = o;
    } else {
        int idx = (blockIdx.x - XCB) * 256 + threadIdx.x;
        size_t e = (size_t)idx * 4;
        const size_t PL = (size_t)NHID * KD;
        int col = (int)(e % KD);
        float4 m;
        if (col < INF) m = *(const float4*)(mask + e);
        else           m = make_float4(1.f, 1.f, 1.f, 1.f);
        const float* Ws[5] = {Wg, Wh, Wfg, Wfh, Wp};
        #pragma unroll
        for (int k = 0; k < 5; ++k) {
            float4 w = *(const float4*)(Ws[k] + e);
            ushort4v o;
            o[0] = f2bf(w.x * m.x); o[1] = f2bf(w.y * m.y);
            o[2] = f2bf(w.z * m.z); o[3] = f2bf(w.w * m.w);
            *(ushort4v*)(Wm + k * PL + e) = o;
        }
    }
}

// ---------------- fused GEMM + epilogue: R6's exact 4-phase loop, fused C ----------------
// Geometry: 256 rows x 64 cols x 5 planes, 8 waves (2M x 4N), 16x16x32 MFMA,
// per-wave 128x80 = acc[8][5]; minimal reads (A 16 + B 10 = 26 b128/wave/tile,
// b0/b1 held in regs across phases). B LDS rows plane-major: row = p*64 + c
// (plane p, col c) so each wave's 5 n-frags = 5 planes of the SAME 16 cols ->
// in-register epilogue. Swizzle K(r)=r&7 via soff (validated 0-conflict).
// Phase form (best measured, R6): {reads ; stage dribble -> bar -> setprio
// 20 MFMA -> bar} x4; ONE vmcnt(0) at P3 end (staged ops ~3 phases old).
#define MFMA16(d, va, vb) d = __builtin_amdgcn_mfma_f32_16x16x32_bf16(va, vb, d, 0, 0, 0)

__global__ __launch_bounds__(512, 2) void gemm_fused(
    const unsigned short* __restrict__ A,
    const unsigned short* __restrict__ Bm,
    const float* __restrict__ bg, const float* __restrict__ bh,
    const float* __restrict__ bfg, const float* __restrict__ bfh,
    const float* __restrict__ bp,
    float* __restrict__ out) {
    __shared__ unsigned short lsA[2][256 * 64];   // 64 KB
    __shared__ unsigned short lsB[2][320 * 64];   // 80 KB

    const int tid  = threadIdx.x;
    const int lane = tid & 63;
    const int w    = tid >> 6;       // 0..7
    const int wm   = w >> 2;         // 0..1  (M waves)
    const int wn   = w & 3;          // 0..3  (N col-quarter)
    const int lr   = lane & 15;
    const int kq   = lane >> 4;      // 0..3
    const int l7   = lane & 7;
    const int m0   = blockIdx.y * 256;
    const int n0c  = blockIdx.x * 64;

    const unsigned short* gA = A + (size_t)m0 * KD;
    // staging: 8 rows x 8 slots per instr; stored key K(r) = r&7
    const int soff = (lane >> 3) * KD + (((lane & 7) ^ (lane >> 3)) << 3);
    const int ar0 = (w >> 2) * 128 + (w & 3) * 8;  // + 32*j, j=0..3
    const int br0 = (w >> 1) * 80 + (w & 1) * 8;   // + 16*j, j=0..4

#define SA(j, t, b) __builtin_amdgcn_global_load_lds( \
        (const AS1 unsigned int*)(gA + (size_t)(ar0 + 32 * (j)) * KD + (t) * 64 + soff), \
        (AS3 unsigned int*)(&lsA[b][(ar0 + 32 * (j)) * 64]), 16, 0, 0)
#define SB(j, t, b) do { \
        const int r0_ = br0 + 16 * (j); \
        const int grow_ = (r0_ >> 6) * NHID + n0c + (r0_ & 63); \
        __builtin_amdgcn_global_load_lds( \
            (const AS1 unsigned int*)(Bm + (size_t)grow_ * KD + (t) * 64 + soff), \
            (AS3 unsigned int*)(&lsB[b][r0_ * 64]), 16, 0, 0); \
    } while (0)

    // reads: row key = row&7 = l7 (all read-row strides are multiples of 8)
    const int c0 = ((0 + kq) ^ l7) << 3;   // k-half 0 (ushort offset)
    const int c1 = ((4 + kq) ^ l7) << 3;   // k-half 1
    const int arow  = wm * 128 + lr;       // + 16*m
    const int browb = wn * 16 + lr;        // + 64*p (plane-major)

#define LDA(b, m, cs) (*(const short8*)&lsA[b][(arow + 16 * (m)) * 64 + (cs)])
#define LDB(b, p, cs) (*(const short8*)&lsB[b][((p) * 64 + browb) * 64 + (cs)])

#define PBAR() do { __builtin_amdgcn_s_barrier(); \
                    __builtin_amdgcn_sched_barrier(0); } while (0)

    f32x4 acc[8][5] = {};

    // prologue: stage kt=0 into buf 0
    SA(0, 0, 0); SA(1, 0, 0); SA(2, 0, 0); SA(3, 0, 0);
    SB(0, 0, 0); SB(1, 0, 0); SB(2, 0, 0); SB(3, 0, 0); SB(4, 0, 0);
    asm volatile("s_waitcnt vmcnt(0)" ::: "memory");
    __builtin_amdgcn_s_barrier();

    for (int kt = 0; kt < NS; ++kt) {
        const int bc = kt & 1, bo = bc ^ 1;
        const bool st = (kt + 1 < NS);
        short8 aL[4], aH[4], b0[5], b1[5];

        // ---- P0: M 0-3, K-half 0 ----
        #pragma unroll
        for (int m = 0; m < 4; ++m) aL[m] = LDA(bc, m, c0);
        #pragma unroll
        for (int n = 0; n < 5; ++n) b0[n] = LDB(bc, n, c0);
        if (st) { SA(0, kt + 1, bo); SA(1, kt + 1, bo); SA(2, kt + 1, bo); }
        PBAR();
        __builtin_amdgcn_s_setprio(1);
        #pragma unroll
        for (int m = 0; m < 4; ++m)
            #pragma unroll
            for (int n = 0; n < 5; ++n) MFMA16(acc[m][n], aL[m], b0[n]);
        __builtin_amdgcn_s_setprio(0);
        PBAR();

        // ---- P1: M 0-3, K-half 1 ----
        #pragma unroll
        for (int m = 0; m < 4; ++m) aL[m] = LDA(bc, m, c1);
        #pragma unroll
        for (int n = 0; n < 5; ++n) b1[n] = LDB(bc, n, c1);
        if (st) { SA(3, kt + 1, bo); SB(0, kt + 1, bo); SB(1, kt + 1, bo); }
        PBAR();
        __builtin_amdgcn_s_setprio(1);
        #pragma unroll
        for (int m = 0; m < 4; ++m)
            #pragma unroll
            for (int n = 0; n < 5; ++n) MFMA16(acc[m][n], aL[m], b1[n]);
        __builtin_amdgcn_s_setprio(0);
        PBAR();

        // ---- P2: M 4-7, K-half 0 (b0 held live) ----
        #pragma unroll
        for (int m = 0; m < 4; ++m) aH[m] = LDA(bc, 4 + m, c0);
        if (st) { SB(2, kt + 1, bo); SB(3, kt + 1, bo); SB(4, kt + 1, bo); }
        PBAR();
        __builtin_amdgcn_s_setprio(1);
        #pragma unroll
        for (int m = 0; m < 4; ++m)
            #pragma unroll
            for (int n = 0; n < 5; ++n) MFMA16(acc[4 + m][n], aH[m], b0[n]);
        __builtin_amdgcn_s_setprio(0);
        PBAR();

        // ---- P3: M 4-7, K-half 1 (b1 held live) ----
        #pragma unroll
        for (int m = 0; m < 4; ++m) aH[m] = LDA(bc, 4 + m, c1);
        PBAR();
        __builtin_amdgcn_s_setprio(1);
        #pragma unroll
        for (int m = 0; m < 4; ++m)
            #pragma unroll
            for (int n = 0; n < 5; ++n) MFMA16(acc[4 + m][n], aH[m], b1[n]);
        __builtin_amdgcn_s_setprio(0);
        // flip gate: staged loads for kt+1 are >=1 phase old -> near-free drain
        asm volatile("s_waitcnt vmcnt(0)" ::: "memory");
        __builtin_amdgcn_s_barrier();
    }

    // ---- fused epilogue (16x16 C/D: col = lane&15, row = m*16 + kq*4 + j) ----
    const int col = n0c + wn * 16 + lr;
    const float bgv = bg[col];
    const float bhv = bh[col];
    const float bfv = bfg[col] + bfh[col];
    const float bpv = bp[col];
    const size_t PL = (size_t)MDIM * NHID;
    #pragma unroll
    for (int m = 0; m < 8; ++m) {
        #pragma unroll
        for (int j = 0; j < 4; ++j) {
            const int row = m0 + wm * 128 + m * 16 + kq * 4 + j;
            float gx = acc[m][0][j] + bgv;
            float hx = acc[m][1][j] + bhv;
            float sx = acc[m][2][j] + acc[m][3][j] + bfv;
            float tg = __expf(-2.0f * fabsf(gx));
            float g  = __builtin_copysignf((1.0f - tg) / (1.0f + tg), gx);
            float th = __expf(-2.0f * fabsf(hx));
            float hh = __builtin_copysignf((1.0f - th) / (1.0f + th), hx);
            float gate = 1.0f / (1.0f + __expf(-sx));
            float nh = g * (1.0f - gate) + gate * hh;
            float y  = acc[m][4][j] + bpv + nh;
            out[(size_t)row * NHID + col]      = y;
            out[PL + (size_t)row * NHID + col] = nh;
        }
    }
#undef SA
#undef SB
#undef LDA
#undef LDB
#undef PBAR
}

extern "C" void kernel_launch(void* const* d_in, const int* in_sizes, int n_in,
                              void* d_out, int out_size, void* d_ws, size_t ws_size,
                              hipStream_t stream) {
    const float* x      = (const float*)d_in[0];
    const float* hidden = (const float*)d_in[1];
    const float* mask   = (const float*)d_in[2];
    const float* Wg     = (const float*)d_in[3];
    const float* bg     = (const float*)d_in[4];
    const float* Wh     = (const float*)d_in[5];
    const float* bh     = (const float*)d_in[6];
    const float* Wfg    = (const float*)d_in[7];
    const float* bfg    = (const float*)d_in[8];
    const float* Wfh    = (const float*)d_in[9];
    const float* bfh    = (const float*)d_in[10];
    const float* Wp     = (const float*)d_in[11];
    const float* bp     = (const float*)d_in[12];
    float* out = (float*)d_out;

    const size_t need = (size_t)MDIM * KD * 2 + (size_t)5 * NHID * KD * 2;
    if (ws_size < need) return;

    unsigned short* xc = (unsigned short*)d_ws;
    unsigned short* Wm = xc + (size_t)MDIM * KD;

    prep_all<<<XCB + NHID * KD / 4 / 256, 256, 0, stream>>>(
        x, hidden, xc, Wg, Wh, Wfg, Wfh, Wp, mask, Wm);
    dim3 grid(NHID / 64, MDIM / 256);
    gemm_fused<<<grid, 512, 0, stream>>>(xc, Wm, bg, bh, bfg, bfh, bp, out);
}